// Round 1
// baseline (482.186 us; speedup 1.0000x reference)
//
#include <hip/hip_runtime.h>
#include <hip/hip_bf16.h>
#include <stdint.h>

// ---------------------------------------------------------------------------
// QLoRALinear: out[m,o] = sum_i x[m,i] * (NF4[codes[o,i]]*absmax[o,i/64]) + bias[o]
//                         + 2.0 * sum_r (x@A)[m,r] * B[r,o]
// Strategy: fold LoRA into dequantized weights -> one bf16 MFMA GEMM.
//   ws layout: [ x_bf16 : M*K bf16 ][ W_eff : N*K bf16 (B^T layout, [N][K]) ]
// GEMM: m97-verified structure, 128x128 tile, BK=32, 4 waves (2x2), 16x16x32 MFMA,
//       global_load_lds width=16 staging, 2 barriers / K-step.
// ---------------------------------------------------------------------------

typedef __bf16 bf16x8 __attribute__((ext_vector_type(8)));
typedef float  f32x4  __attribute__((ext_vector_type(8/2)));
typedef unsigned short u16x8 __attribute__((ext_vector_type(8)));

__constant__ float NF4_TAB[16] = {
    -1.0f, -0.6961928009986877f, -0.5250730514526367f, -0.39491748809814453f,
    -0.28444138169288635f, -0.18477343022823334f, -0.09105003625154495f, 0.0f,
    0.07958029955625534f, 0.16093020141124725f, 0.24611230194568634f,
    0.33791524171829224f, 0.44070982933044434f, 0.5626170039176941f,
    0.7229568362236023f, 1.0f};

__device__ __forceinline__ unsigned short f2bf(float f) {
    unsigned int u = __float_as_uint(f);
    u += 0x7FFFu + ((u >> 16) & 1u);          // round-to-nearest-even
    return (unsigned short)(u >> 16);
}

// ---- prep 1: x fp32 -> bf16 (8 elems/thread, float4 x2 in, 16B out) --------
__global__ __launch_bounds__(256) void cvt_x_kernel(
    const float* __restrict__ x, unsigned short* __restrict__ xb, int n8) {
    int i = blockIdx.x * 256 + threadIdx.x;
    if (i >= n8) return;
    const float4* p = (const float4*)x + (long)i * 2;
    float4 a = p[0], b = p[1];
    u16x8 o;
    o[0] = f2bf(a.x); o[1] = f2bf(a.y); o[2] = f2bf(a.z); o[3] = f2bf(a.w);
    o[4] = f2bf(b.x); o[5] = f2bf(b.y); o[6] = f2bf(b.z); o[7] = f2bf(b.w);
    *((u16x8*)xb + i) = o;
}

// ---- prep 2: W_eff[o,i] = NF4[code]*absmax + 2*sum_r A[i,r]*B[r,o] (bf16) --
// grid: (I/2048, O); 256 threads, 8 consecutive i per thread.
__global__ __launch_bounds__(256) void build_w_kernel(
    const int* __restrict__ codes, const float* __restrict__ absmax,
    const float* __restrict__ lA, const float* __restrict__ lB,
    unsigned short* __restrict__ W, int O, int I) {
    const int o  = blockIdx.y;
    const int i0 = blockIdx.x * 2048 + threadIdx.x * 8;
    float bo[8];
#pragma unroll
    for (int r = 0; r < 8; ++r) bo[r] = lB[(long)r * O + o] * 2.0f;  // SCALING=16/8
    const long base = (long)o * I + i0;
    const int4* cp = (const int4*)(codes + base);
    int4 c0 = cp[0], c1 = cp[1];
    const float am = absmax[o * (I >> 6) + (i0 >> 6)];   // 8 elems within one 64-block
    int cc[8] = {c0.x, c0.y, c0.z, c0.w, c1.x, c1.y, c1.z, c1.w};
    u16x8 ov;
#pragma unroll
    for (int j = 0; j < 8; ++j) {
        const float4* ap = (const float4*)(lA + (long)(i0 + j) * 8);
        float4 a0 = ap[0], a1 = ap[1];
        float w = NF4_TAB[cc[j] & 15] * am;
        w += a0.x * bo[0] + a0.y * bo[1] + a0.z * bo[2] + a0.w * bo[3]
           + a1.x * bo[4] + a1.y * bo[5] + a1.z * bo[6] + a1.w * bo[7];
        ov[j] = f2bf(w);
    }
    *(u16x8*)(W + base) = ov;
}

// ---- main GEMM: out = x_bf16 @ W_eff^T + bias ------------------------------
#define BM 128
#define BN 128
#define BK 32

#define GLOAD(g, s) __builtin_amdgcn_global_load_lds(                      \
    (const __attribute__((address_space(1))) void*)(g),                    \
    (__attribute__((address_space(3))) void*)(s), 16, 0, 0)

__global__ __launch_bounds__(256) void gemm_kernel(
    const unsigned short* __restrict__ A,   // [M][K] bf16 bits
    const unsigned short* __restrict__ B,   // [N][K] bf16 bits (B^T form)
    const float* __restrict__ bias,
    float* __restrict__ out, int M, int N, int K) {
    __shared__ unsigned short sA[BM * BK];   // 8 KiB
    __shared__ unsigned short sB[BN * BK];   // 8 KiB

    const int t = threadIdx.x;
    const int w = t >> 6;          // wave 0..3
    const int l = t & 63;
    const int mB = blockIdx.y * BM;
    const int nB = blockIdx.x * BN;
    const int wr = w >> 1, wc = w & 1;      // 2x2 wave grid, 64x64 out each

    // staging: each wave owns segments {2w, 2w+1}; a segment = 16 rows x 64B.
    // global_load_lds writes lds_base + lane*16 (wave-uniform base).
    const int s0 = 2 * w, s1 = s0 + 1;
    const int lrow = l >> 2;            // 0..15 row within segment
    const int lcb  = (l & 3) * 16;      // 0/16/32/48 byte col offset
    const char* gA0 = (const char*)(A + (long)(mB + s0 * 16 + lrow) * K) + lcb;
    const char* gA1 = (const char*)(A + (long)(mB + s1 * 16 + lrow) * K) + lcb;
    const char* gB0 = (const char*)(B + (long)(nB + s0 * 16 + lrow) * K) + lcb;
    const char* gB1 = (const char*)(B + (long)(nB + s1 * 16 + lrow) * K) + lcb;
    char* lA0 = (char*)sA + s0 * 1024;
    char* lA1 = (char*)sA + s1 * 1024;
    char* lB0 = (char*)sB + s0 * 1024;
    char* lB1 = (char*)sB + s1 * 1024;

    // fragment read offsets (elements): row-major [128][BK] tiles
    const int cl = l & 15;
    const int kq = (l >> 4) * 8;
    const int aoffs = (wr * 64 + cl) * BK + kq;
    const int boffs = (wc * 64 + cl) * BK + kq;

    f32x4 acc[4][4];
#pragma unroll
    for (int mi = 0; mi < 4; ++mi)
#pragma unroll
        for (int ni = 0; ni < 4; ++ni) acc[mi][ni] = (f32x4){0.f, 0.f, 0.f, 0.f};

    for (int kt = 0; kt < K; kt += BK) {
        GLOAD(gA0, lA0); GLOAD(gA1, lA1);
        GLOAD(gB0, lB0); GLOAD(gB1, lB1);
        gA0 += 2 * BK; gA1 += 2 * BK; gB0 += 2 * BK; gB1 += 2 * BK;
        __syncthreads();   // drains vmcnt before barrier -> LDS tile ready
        bf16x8 af[4], bv[4];
#pragma unroll
        for (int mi = 0; mi < 4; ++mi)
            af[mi] = *reinterpret_cast<const bf16x8*>(sA + aoffs + mi * 16 * BK);
#pragma unroll
        for (int ni = 0; ni < 4; ++ni)
            bv[ni] = *reinterpret_cast<const bf16x8*>(sB + boffs + ni * 16 * BK);
#pragma unroll
        for (int mi = 0; mi < 4; ++mi)
#pragma unroll
            for (int ni = 0; ni < 4; ++ni)
                acc[mi][ni] = __builtin_amdgcn_mfma_f32_16x16x32_bf16(
                    af[mi], bv[ni], acc[mi][ni], 0, 0, 0);
        __syncthreads();   // protect LDS from next-iter staging
    }

    // epilogue: D lane mapping col = l&15, row = (l>>4)*4 + r  [m89/m91]
    float bsv[4];
#pragma unroll
    for (int ni = 0; ni < 4; ++ni) bsv[ni] = bias[nB + wc * 64 + ni * 16 + cl];
#pragma unroll
    for (int mi = 0; mi < 4; ++mi)
#pragma unroll
        for (int r = 0; r < 4; ++r) {
            long grow = mB + wr * 64 + mi * 16 + (l >> 4) * 4 + r;
            float* op = out + grow * N + nB + wc * 64 + cl;
#pragma unroll
            for (int ni = 0; ni < 4; ++ni)
                op[ni * 16] = acc[mi][ni][r] + bsv[ni];
        }
}

// ---- fallback (only if ws too small / odd shapes): naive, slow, correct ----
__global__ void naive_kernel(const float* __restrict__ x, const int* __restrict__ codes,
                             const float* __restrict__ absmax, const float* __restrict__ bias,
                             const float* __restrict__ lA, const float* __restrict__ lB,
                             float* __restrict__ out, int M, int I, int O) {
    long idx = (long)blockIdx.x * 256 + threadIdx.x;
    if (idx >= (long)M * O) return;
    int o = (int)(idx % O);
    long m = idx / O;
    const float* xr = x + m * I;
    const int* cr = codes + (long)o * I;
    const float* ar = absmax + (long)o * (I >> 6);
    float acc = 0.f;
    float la[8] = {0, 0, 0, 0, 0, 0, 0, 0};
    for (int i = 0; i < I; ++i) {
        float xv = xr[i];
        acc += xv * NF4_TAB[cr[i] & 15] * ar[i >> 6];
        const float* av = lA + (long)i * 8;
#pragma unroll
        for (int r = 0; r < 8; ++r) la[r] += xv * av[r];
    }
    float lv = 0.f;
#pragma unroll
    for (int r = 0; r < 8; ++r) lv += la[r] * lB[(long)r * O + o];
    out[idx] = acc + bias[o] + 2.0f * lv;
}

extern "C" void kernel_launch(void* const* d_in, const int* in_sizes, int n_in,
                              void* d_out, int out_size, void* d_ws, size_t ws_size,
                              hipStream_t stream) {
    const float* x      = (const float*)d_in[0];
    const int*   codes  = (const int*)d_in[1];
    const float* absmax = (const float*)d_in[2];
    const float* bias   = (const float*)d_in[3];
    const float* lA     = (const float*)d_in[4];
    const float* lB     = (const float*)d_in[5];
    float* out = (float*)d_out;

    const int I = in_sizes[4] / 8;     // lora_A is [I][8]
    const int O = in_sizes[3];         // bias is [O]
    const int M = in_sizes[0] / I;     // x is [M][I] flattened
    const int K = I;

    const size_t need = (size_t)M * K * 2 + (size_t)O * K * 2;
    if (ws_size < need || (M % BM) || (O % BN) || (K % 2048)) {
        long tot = (long)M * O;
        naive_kernel<<<(int)((tot + 255) / 256), 256, 0, stream>>>(
            x, codes, absmax, bias, lA, lB, out, M, I, O);
        return;
    }

    unsigned short* xb = (unsigned short*)d_ws;          // [M][K] bf16
    unsigned short* wb = xb + (size_t)M * K;             // [O][K] bf16 (B^T)

    const int n8 = (M * K) / 8;
    cvt_x_kernel<<<(n8 + 255) / 256, 256, 0, stream>>>(x, xb, n8);
    dim3 gw(K / 2048, O);
    build_w_kernel<<<gw, 256, 0, stream>>>(codes, absmax, lA, lB, wb, O, K);
    dim3 grid(O / BN, M / BM);
    gemm_kernel<<<grid, 256, 0, stream>>>(xb, wb, bias, out, M, O, K);
}

// Round 2
// 350.353 us; speedup vs baseline: 1.3763x; 1.3763x over previous
//
#include <hip/hip_runtime.h>
#include <hip/hip_bf16.h>
#include <stdint.h>

// ---------------------------------------------------------------------------
// QLoRALinear: out = x @ (NF4dq(codes,absmax) + 2*A@B)^T + bias
// R2: 256x256 8-wave 4-phase/K-tile double-buffered MFMA GEMM (T2+T3+T4+T5),
//     provably race-free staging schedule, counted vmcnt (never 0 in loop).
// ---------------------------------------------------------------------------

typedef __bf16 bf16x8 __attribute__((ext_vector_type(8)));
typedef float  f32x4  __attribute__((ext_vector_type(4)));
typedef unsigned short u16x8 __attribute__((ext_vector_type(8)));

__constant__ float NF4_TAB[16] = {
    -1.0f, -0.6961928009986877f, -0.5250730514526367f, -0.39491748809814453f,
    -0.28444138169288635f, -0.18477343022823334f, -0.09105003625154495f, 0.0f,
    0.07958029955625534f, 0.16093020141124725f, 0.24611230194568634f,
    0.33791524171829224f, 0.44070982933044434f, 0.5626170039176941f,
    0.7229568362236023f, 1.0f};

__device__ __forceinline__ unsigned short f2bf(float f) {
    unsigned int u = __float_as_uint(f);
    u += 0x7FFFu + ((u >> 16) & 1u);
    return (unsigned short)(u >> 16);
}

// ---- prep 1: x fp32 -> bf16 ------------------------------------------------
__global__ __launch_bounds__(256) void cvt_x_kernel(
    const float* __restrict__ x, unsigned short* __restrict__ xb, int n8) {
    int i = blockIdx.x * 256 + threadIdx.x;
    if (i >= n8) return;
    const float4* p = (const float4*)x + (long)i * 2;
    float4 a = p[0], b = p[1];
    u16x8 o;
    o[0] = f2bf(a.x); o[1] = f2bf(a.y); o[2] = f2bf(a.z); o[3] = f2bf(a.w);
    o[4] = f2bf(b.x); o[5] = f2bf(b.y); o[6] = f2bf(b.z); o[7] = f2bf(b.w);
    *((u16x8*)xb + i) = o;
}

// ---- prep 2: W_eff[o,i] = NF4[code]*absmax + 2*sum_r A[i,r]*B[r,o] ---------
__global__ __launch_bounds__(256) void build_w_kernel(
    const int* __restrict__ codes, const float* __restrict__ absmax,
    const float* __restrict__ lA, const float* __restrict__ lB,
    unsigned short* __restrict__ W, int O, int I) {
    const int o  = blockIdx.y;
    const int i0 = blockIdx.x * 2048 + threadIdx.x * 8;
    float bo[8];
#pragma unroll
    for (int r = 0; r < 8; ++r) bo[r] = lB[(long)r * O + o] * 2.0f;
    const long base = (long)o * I + i0;
    const int4* cp = (const int4*)(codes + base);
    int4 c0 = cp[0], c1 = cp[1];
    const float am = absmax[o * (I >> 6) + (i0 >> 6)];
    int cc[8] = {c0.x, c0.y, c0.z, c0.w, c1.x, c1.y, c1.z, c1.w};
    u16x8 ov;
#pragma unroll
    for (int j = 0; j < 8; ++j) {
        const float4* ap = (const float4*)(lA + (long)(i0 + j) * 8);
        float4 a0 = ap[0], a1 = ap[1];
        float w = NF4_TAB[cc[j] & 15] * am;
        w += a0.x * bo[0] + a0.y * bo[1] + a0.z * bo[2] + a0.w * bo[3]
           + a1.x * bo[4] + a1.y * bo[5] + a1.z * bo[6] + a1.w * bo[7];
        ov[j] = f2bf(w);
    }
    *(u16x8*)(W + base) = ov;
}

// ---- main GEMM: 256x256 tile, BK=64, 8 waves, 4-phase schedule -------------
#define BM 256
#define BN 256
#define BK 64

#define GLOAD16(g, s) __builtin_amdgcn_global_load_lds(                     \
    (const __attribute__((address_space(1))) void*)(g),                     \
    (__attribute__((address_space(3))) void*)(s), 16, 0, 0)

// issue one half-tile (128 rows x 64 cols bf16 = 16KB) as 2 x glds per thread
#define STAGE(ptr, ldsbase) do {                                            \
    GLOAD16((ptr), (char*)(ldsbase) + ldsW);                                \
    GLOAD16((ptr) + SK, (char*)(ldsbase) + 8192 + ldsW); } while (0)

// raw barrier with compiler-level memory fence (no vmcnt(0) drain emitted)
#define BAR() do { asm volatile("" ::: "memory");                           \
    __builtin_amdgcn_s_barrier(); asm volatile("" ::: "memory"); } while (0)

#define MFMA_QUAD(H, KQ, BREG)                                              \
    _Pragma("unroll") for (int mi = 0; mi < 4; ++mi)                        \
    _Pragma("unroll") for (int ni = 0; ni < 2; ++ni) {                      \
        acc[H][KQ][mi][ni] = __builtin_amdgcn_mfma_f32_16x16x32_bf16(       \
            a[mi][0], BREG[ni][0], acc[H][KQ][mi][ni], 0, 0, 0);            \
        acc[H][KQ][mi][ni] = __builtin_amdgcn_mfma_f32_16x16x32_bf16(       \
            a[mi][1], BREG[ni][1], acc[H][KQ][mi][ni], 0, 0, 0); }

__global__ __launch_bounds__(512, 2) void gemm_kernel(
    const unsigned short* __restrict__ A,   // [M][K] bf16 bits
    const unsigned short* __restrict__ Bm,  // [N][K] bf16 bits
    const float* __restrict__ bias,
    float* __restrict__ out, int M, int N, int K) {
    // per buffer: A tile [256][64] bf16 rows at r*128 (swizzled in-row),
    //             bytes [0,32768); B tile at [32768,65536). 2 buffers = 128KB.
    __shared__ char lds[2][65536];

    const int t = threadIdx.x;
    const int w = t >> 6, l = t & 63;
    const int wr = w >> 2, wc = w & 3;              // 2x4 wave grid per quadrant
    const long mB = (long)blockIdx.y * BM;
    const long nB = (long)blockIdx.x * BN;
    const int NT = K / BK;

    // staging thread constants. LDS write is linear (base + lane*16); the
    // in-row swizzle is applied by permuting the GLOBAL source column:
    // LDS row r holds col-block cb at physical slot (cb ^ (r&7)).
    const int sRow = w * 8 + (l >> 3);              // r&7 == l>>3
    const int sCol = ((l & 7) ^ (l >> 3)) << 3;     // source elem col
    const int ldsW = w * 1024;                      // wave's 8-row chunk
    const long SK = 64L * K;                        // set-1 row offset (elems)
    const long HK = 128L * K;                       // half-1 row offset
    const unsigned short* gA = A  + (mB + sRow) * K + sCol;
    const unsigned short* gB = Bm + (nB + sRow) * K + sCol;

    // rolling staging sources (advance 64 elems/K-tile)
    const unsigned short* pA1 = gA + HK + BK;       // (g+1).A-half1
    const unsigned short* pB1 = gB + HK + BK;
    const unsigned short* pA0 = gA + 2 * BK;        // (g+2).A-half0
    const unsigned short* pB0 = gB + 2 * BK;

    // fragment-read lane constants (swizzled ds_read slot); r&7 == l&7
    const int fr = l & 15;
    const int aoff0 = fr * 128 + ((((l >> 4)) ^ (l & 7)) << 4);   // kk=0
    const int aoff1 = fr * 128 + (((4 + (l >> 4)) ^ (l & 7)) << 4); // kk=1

    f32x4 acc[2][2][4][2];
#pragma unroll
    for (int h = 0; h < 2; ++h)
#pragma unroll
        for (int k = 0; k < 2; ++k)
#pragma unroll
            for (int mi = 0; mi < 4; ++mi)
#pragma unroll
                for (int ni = 0; ni < 2; ++ni)
                    acc[h][k][mi][ni] = (f32x4){0.f, 0.f, 0.f, 0.f};

    // ---- prologue: tile0 all 4 halves -> buf0; tile1 A0,B0 -> buf1
    STAGE(gA,      lds[0] + 0);
    STAGE(gA + HK, lds[0] + 16384);
    STAGE(gB,      lds[0] + 32768);
    STAGE(gB + HK, lds[0] + 49152);
    STAGE(gA + BK, lds[1] + 0);
    STAGE(gB + BK, lds[1] + 32768);
    asm volatile("s_waitcnt vmcnt(4)" ::: "memory");  // tile0 resident
    BAR();

    bf16x8 a[4][2], b0[2][2], b1[2][2];

    for (int g = 0; g < NT; ++g) {
        char* cur = lds[g & 1];
        char* nxt = lds[(g & 1) ^ 1];
        const char* Ab = cur + wr * 8192;           // + h*16384 + mi*2048
        const char* Bb = cur + 32768 + wc * 4096;   // + k*16384 + ni*2048
        const bool st1 = (g + 1 < NT), st2 = (g + 2 < NT);

        // phase 1: quad(0,0). reads A0,B0 frags; stage (g+1).A1 -> nxt.A1
#pragma unroll
        for (int mi = 0; mi < 4; ++mi) {
            a[mi][0] = *(const bf16x8*)(Ab + mi * 2048 + aoff0);
            a[mi][1] = *(const bf16x8*)(Ab + mi * 2048 + aoff1);
        }
#pragma unroll
        for (int ni = 0; ni < 2; ++ni) {
            b0[ni][0] = *(const bf16x8*)(Bb + ni * 2048 + aoff0);
            b0[ni][1] = *(const bf16x8*)(Bb + ni * 2048 + aoff1);
        }
        if (st1) STAGE(pA1, nxt + 16384);
        BAR();
        __builtin_amdgcn_s_setprio(1);
        MFMA_QUAD(0, 0, b0);
        __builtin_amdgcn_s_setprio(0);

        // phase 2: quad(0,1). reads B1 frags (reuse a); stage (g+1).B1
#pragma unroll
        for (int ni = 0; ni < 2; ++ni) {
            b1[ni][0] = *(const bf16x8*)(Bb + 16384 + ni * 2048 + aoff0);
            b1[ni][1] = *(const bf16x8*)(Bb + 16384 + ni * 2048 + aoff1);
        }
        if (st1) STAGE(pB1, nxt + 49152);
        BAR();
        __builtin_amdgcn_s_setprio(1);
        MFMA_QUAD(0, 1, b1);
        __builtin_amdgcn_s_setprio(0);

        // phase 3: quad(1,0). reads A1 frags (reuse b0); stage (g+2).A0 -> cur.A0
        //   (cur.A0 last LDS-read in phase 1; all waves past phase-2 barrier)
#pragma unroll
        for (int mi = 0; mi < 4; ++mi) {
            a[mi][0] = *(const bf16x8*)(Ab + 16384 + mi * 2048 + aoff0);
            a[mi][1] = *(const bf16x8*)(Ab + 16384 + mi * 2048 + aoff1);
        }
        if (st2) STAGE(pA0, cur + 0);
        BAR();
        __builtin_amdgcn_s_setprio(1);
        MFMA_QUAD(1, 0, b0);
        __builtin_amdgcn_s_setprio(0);

        // phase 4: quad(1,1). no new reads; stage (g+2).B0 -> cur.B0;
        // counted vmcnt: allow the 2 newest half-tiles (tile g+2) in flight.
        if (st2) STAGE(pB0, cur + 32768);
        if (st2) { asm volatile("s_waitcnt vmcnt(4)" ::: "memory"); }
        else     { asm volatile("s_waitcnt vmcnt(0)" ::: "memory"); }
        BAR();
        __builtin_amdgcn_s_setprio(1);
        MFMA_QUAD(1, 1, b1);
        __builtin_amdgcn_s_setprio(0);

        pA1 += BK; pB1 += BK; pA0 += BK; pB0 += BK;
    }

    // ---- epilogue: D mapping col=l&15, row=(l>>4)*4+r; add bias ------------
    const int r4 = (l >> 4) * 4;
#pragma unroll
    for (int kq = 0; kq < 2; ++kq) {
        float bs[2];
#pragma unroll
        for (int ni = 0; ni < 2; ++ni)
            bs[ni] = bias[nB + kq * 128 + wc * 32 + ni * 16 + fr];
#pragma unroll
        for (int h = 0; h < 2; ++h)
#pragma unroll
            for (int mi = 0; mi < 4; ++mi)
#pragma unroll
                for (int r = 0; r < 4; ++r) {
                    long row = mB + h * 128 + wr * 64 + mi * 16 + r4 + r;
                    float* op = out + row * N + nB + kq * 128 + wc * 32 + fr;
#pragma unroll
                    for (int ni = 0; ni < 2; ++ni)
                        op[ni * 16] = acc[h][kq][mi][ni][r] + bs[ni];
                }
    }
}

// ---- fallback: naive, slow, correct ---------------------------------------
__global__ void naive_kernel(const float* __restrict__ x, const int* __restrict__ codes,
                             const float* __restrict__ absmax, const float* __restrict__ bias,
                             const float* __restrict__ lA, const float* __restrict__ lB,
                             float* __restrict__ out, int M, int I, int O) {
    long idx = (long)blockIdx.x * 256 + threadIdx.x;
    if (idx >= (long)M * O) return;
    int o = (int)(idx % O);
    long m = idx / O;
    const float* xr = x + m * I;
    const int* cr = codes + (long)o * I;
    const float* ar = absmax + (long)o * (I >> 6);
    float acc = 0.f;
    float la[8] = {0, 0, 0, 0, 0, 0, 0, 0};
    for (int i = 0; i < I; ++i) {
        float xv = xr[i];
        acc += xv * NF4_TAB[cr[i] & 15] * ar[i >> 6];
        const float* av = lA + (long)i * 8;
#pragma unroll
        for (int r = 0; r < 8; ++r) la[r] += xv * av[r];
    }
    float lv = 0.f;
#pragma unroll
    for (int r = 0; r < 8; ++r) lv += la[r] * lB[(long)r * O + o];
    out[idx] = acc + bias[o] + 2.0f * lv;
}

extern "C" void kernel_launch(void* const* d_in, const int* in_sizes, int n_in,
                              void* d_out, int out_size, void* d_ws, size_t ws_size,
                              hipStream_t stream) {
    const float* x      = (const float*)d_in[0];
    const int*   codes  = (const int*)d_in[1];
    const float* absmax = (const float*)d_in[2];
    const float* bias   = (const float*)d_in[3];
    const float* lA     = (const float*)d_in[4];
    const float* lB     = (const float*)d_in[5];
    float* out = (float*)d_out;

    const int I = in_sizes[4] / 8;
    const int O = in_sizes[3];
    const int M = in_sizes[0] / I;
    const int K = I;

    const size_t need = (size_t)M * K * 2 + (size_t)O * K * 2;
    if (ws_size < need || (M % BM) || (O % BN) || (K % 2048) || (K / BK) < 2) {
        long tot = (long)M * O;
        naive_kernel<<<(int)((tot + 255) / 256), 256, 0, stream>>>(
            x, codes, absmax, bias, lA, lB, out, M, I, O);
        return;
    }

    unsigned short* xb = (unsigned short*)d_ws;
    unsigned short* wb = xb + (size_t)M * K;

    const int n8 = (M * K) / 8;
    cvt_x_kernel<<<(n8 + 255) / 256, 256, 0, stream>>>(x, xb, n8);
    dim3 gw(K / 2048, O);
    build_w_kernel<<<gw, 256, 0, stream>>>(codes, absmax, lA, lB, wb, O, K);
    dim3 grid(O / BN, M / BM);
    gemm_kernel<<<grid, 512, 0, stream>>>(xb, wb, bias, out, M, O, K);
}